// Round 1
// baseline (195.034 us; speedup 1.0000x reference)
//
#include <hip/hip_runtime.h>
#include <hip/hip_bf16.h>

typedef __attribute__((ext_vector_type(4))) float  f32x4;
typedef __attribute__((ext_vector_type(8))) short  s16x8;
typedef __attribute__((ext_vector_type(4))) unsigned short u16x4;

#define D_MODEL 2048
#define SEQ     4096
#define BATCH   4
#define NATOMS  64
#define RANK    6
#define NLAYERS 16
#define NAR     (NATOMS*RANK)     /* 384 */
#define M_TOTAL (BATCH*SEQ)       /* 16384 */

static __device__ __forceinline__ unsigned short f2bf(float x){
    union { float f; unsigned u; } v; v.f = x;
    unsigned r = (v.u + 0x7FFF + ((v.u >> 16) & 1)) >> 16;
    return (unsigned short)r;
}

// ---------------------------------------------------------------------------
// Prep: gather layer slice, cast to bf16, lay out K-contiguous.
//   WbfT[n][d]  (n = a*6+r, d = 0..2047)   from A[a, l, d, r]
//   BbfT[p][n]  (p = 0..2047, n = a*6+r)   from B[a, l, r, p]
// ---------------------------------------------------------------------------
__global__ void prep_kernel(const float* __restrict__ A,
                            const float* __restrict__ B,
                            const int*   __restrict__ layer_idx,
                            unsigned short* __restrict__ WbfT,
                            unsigned short* __restrict__ BbfT)
{
    const int l = layer_idx[0];
    int idx = blockIdx.x * 256 + threadIdx.x;
    const int total = NAR * D_MODEL;   // 786432
    if (idx < total) {
        int n = idx / D_MODEL, d = idx % D_MODEL;
        int a = n / RANK, r = n % RANK;
        float v = A[((size_t)(a*NLAYERS + l) * D_MODEL + d) * RANK + r];
        WbfT[idx] = f2bf(v);
    } else {
        idx -= total;
        int p = idx / NAR, n = idx % NAR;
        int a = n / RANK, r = n % RANK;
        float v = B[((size_t)(a*NLAYERS + l) * RANK + r) * D_MODEL + p];
        BbfT[idx] = f2bf(v);
    }
}

// ---------------------------------------------------------------------------
// GEMM1: P[m][n] = f2bf( scale[b, n/6] * sum_d hidden[m][d] * WbfT[n][d] )
//   M=16384, K=2048, N=384.  BM=BN=128, BK=64, 4 waves (2x2), 16x16x32 MFMA.
// ---------------------------------------------------------------------------
__global__ __launch_bounds__(256, 2) void gemm1(
    const float*          __restrict__ hidden,  // [16384][2048] fp32
    const float*          __restrict__ scales,  // [4][64]
    const unsigned short* __restrict__ WbfT,    // [384][2048] bf16
    unsigned short*       __restrict__ P)       // [16384][384] bf16
{
    __shared__ unsigned short At[128][72];   // hidden tile, +8 pad
    __shared__ unsigned short Bt[128][72];   // W tile (n-major, k-contig)

    const int m0   = blockIdx.x * 128;
    const int n0   = blockIdx.y * 128;
    const int tid  = threadIdx.x;
    const int lane = tid & 63;
    const int wave = tid >> 6;
    const int wr   = wave >> 1, wc = wave & 1;

    f32x4 acc[4][4] = {};

    for (int k0 = 0; k0 < D_MODEL; k0 += 64) {
        // stage hidden (fp32 -> bf16): 128 rows x 64 cols
        #pragma unroll
        for (int pass = 0; pass < 8; ++pass) {
            int f   = tid + pass * 256;
            int row = f >> 4, c4 = f & 15;
            f32x4 v = *reinterpret_cast<const f32x4*>(
                &hidden[(size_t)(m0 + row) * D_MODEL + k0 + c4 * 4]);
            u16x4 w;
            w.x = f2bf(v.x); w.y = f2bf(v.y); w.z = f2bf(v.z); w.w = f2bf(v.w);
            *reinterpret_cast<u16x4*>(&At[row][c4 * 4]) = w;
        }
        // stage WbfT: 128 n-rows x 64 k-cols (already bf16, k-contig)
        #pragma unroll
        for (int pass = 0; pass < 4; ++pass) {
            int c   = tid + pass * 256;
            int row = c >> 3, c8 = c & 7;
            s16x8 v = *reinterpret_cast<const s16x8*>(
                &WbfT[(size_t)(n0 + row) * D_MODEL + k0 + c8 * 8]);
            *reinterpret_cast<s16x8*>(&Bt[row][c8 * 8]) = v;
        }
        __syncthreads();

        #pragma unroll
        for (int kk = 0; kk < 64; kk += 32) {
            const int krow = kk + (lane >> 4) * 8;
            s16x8 a_frag[4], b_frag[4];
            #pragma unroll
            for (int mi = 0; mi < 4; ++mi)
                a_frag[mi] = *reinterpret_cast<const s16x8*>(
                    &At[wr * 64 + mi * 16 + (lane & 15)][krow]);
            #pragma unroll
            for (int ni = 0; ni < 4; ++ni)
                b_frag[ni] = *reinterpret_cast<const s16x8*>(
                    &Bt[wc * 64 + ni * 16 + (lane & 15)][krow]);
            #pragma unroll
            for (int mi = 0; mi < 4; ++mi)
                #pragma unroll
                for (int ni = 0; ni < 4; ++ni)
                    acc[mi][ni] = __builtin_amdgcn_mfma_f32_16x16x32_bf16(
                        a_frag[mi], b_frag[ni], acc[mi][ni], 0, 0, 0);
        }
        __syncthreads();
    }

    // epilogue: scale by atom_scales[b, n/6], store bf16
    const int bidx = m0 >> 12;            // m0 / 4096
    const int row0 = m0 + wr * 64;
    const int col0 = n0 + wc * 64;
    #pragma unroll
    for (int ni = 0; ni < 4; ++ni) {
        int col  = col0 + ni * 16 + (lane & 15);
        float sc = scales[bidx * NATOMS + col / RANK];
        #pragma unroll
        for (int mi = 0; mi < 4; ++mi) {
            #pragma unroll
            for (int r = 0; r < 4; ++r) {
                int row = row0 + mi * 16 + (lane >> 4) * 4 + r;
                P[(size_t)row * NAR + col] = f2bf(acc[mi][ni][r] * sc);
            }
        }
    }
}

// ---------------------------------------------------------------------------
// GEMM2: out[m][p] = sum_n P[m][n] * BbfT[p][n]
//   M=16384, K=384, N=2048.  BM=BN=128, BK=64.
// ---------------------------------------------------------------------------
__global__ __launch_bounds__(256, 2) void gemm2(
    const unsigned short* __restrict__ P,     // [16384][384] bf16
    const unsigned short* __restrict__ BbfT,  // [2048][384] bf16
    float*                __restrict__ out)   // [16384][2048] fp32
{
    __shared__ unsigned short Pt[128][72];
    __shared__ unsigned short Bt[128][72];

    const int m0   = blockIdx.x * 128;
    const int p0   = blockIdx.y * 128;
    const int tid  = threadIdx.x;
    const int lane = tid & 63;
    const int wave = tid >> 6;
    const int wr   = wave >> 1, wc = wave & 1;

    f32x4 acc[4][4] = {};

    for (int k0 = 0; k0 < NAR; k0 += 64) {
        #pragma unroll
        for (int pass = 0; pass < 4; ++pass) {
            int c   = tid + pass * 256;
            int row = c >> 3, c8 = c & 7;
            s16x8 v = *reinterpret_cast<const s16x8*>(
                &P[(size_t)(m0 + row) * NAR + k0 + c8 * 8]);
            *reinterpret_cast<s16x8*>(&Pt[row][c8 * 8]) = v;
        }
        #pragma unroll
        for (int pass = 0; pass < 4; ++pass) {
            int c   = tid + pass * 256;
            int row = c >> 3, c8 = c & 7;
            s16x8 v = *reinterpret_cast<const s16x8*>(
                &BbfT[(size_t)(p0 + row) * NAR + k0 + c8 * 8]);
            *reinterpret_cast<s16x8*>(&Bt[row][c8 * 8]) = v;
        }
        __syncthreads();

        #pragma unroll
        for (int kk = 0; kk < 64; kk += 32) {
            const int krow = kk + (lane >> 4) * 8;
            s16x8 a_frag[4], b_frag[4];
            #pragma unroll
            for (int mi = 0; mi < 4; ++mi)
                a_frag[mi] = *reinterpret_cast<const s16x8*>(
                    &Pt[wr * 64 + mi * 16 + (lane & 15)][krow]);
            #pragma unroll
            for (int ni = 0; ni < 4; ++ni)
                b_frag[ni] = *reinterpret_cast<const s16x8*>(
                    &Bt[wc * 64 + ni * 16 + (lane & 15)][krow]);
            #pragma unroll
            for (int mi = 0; mi < 4; ++mi)
                #pragma unroll
                for (int ni = 0; ni < 4; ++ni)
                    acc[mi][ni] = __builtin_amdgcn_mfma_f32_16x16x32_bf16(
                        a_frag[mi], b_frag[ni], acc[mi][ni], 0, 0, 0);
        }
        __syncthreads();
    }

    const int row0 = m0 + wr * 64;
    const int col0 = p0 + wc * 64;
    #pragma unroll
    for (int mi = 0; mi < 4; ++mi) {
        #pragma unroll
        for (int ni = 0; ni < 4; ++ni) {
            int col = col0 + ni * 16 + (lane & 15);
            #pragma unroll
            for (int r = 0; r < 4; ++r) {
                int row = row0 + mi * 16 + (lane >> 4) * 4 + r;
                out[(size_t)row * D_MODEL + col] = acc[mi][ni][r];
            }
        }
    }
}

extern "C" void kernel_launch(void* const* d_in, const int* in_sizes, int n_in,
                              void* d_out, int out_size, void* d_ws, size_t ws_size,
                              hipStream_t stream)
{
    const float* hidden    = (const float*)d_in[0];
    const float* scales    = (const float*)d_in[1];
    const float* A         = (const float*)d_in[2];
    const float* B         = (const float*)d_in[3];
    const int*   layer_idx = (const int*)d_in[4];
    float* out = (float*)d_out;

    unsigned short* WbfT = (unsigned short*)d_ws;            // [384][2048]
    unsigned short* BbfT = WbfT + (size_t)NAR * D_MODEL;     // [2048][384]
    unsigned short* P    = BbfT + (size_t)D_MODEL * NAR;     // [16384][384]

    prep_kernel<<<(2 * NAR * D_MODEL) / 256, 256, 0, stream>>>(A, B, layer_idx, WbfT, BbfT);
    gemm1<<<dim3(M_TOTAL / 128, NAR / 128), 256, 0, stream>>>(hidden, scales, WbfT, P);
    gemm2<<<dim3(M_TOTAL / 128, D_MODEL / 128), 256, 0, stream>>>(P, BbfT, out);
}

// Round 2
// 112.411 us; speedup vs baseline: 1.7350x; 1.7350x over previous
//
#include <hip/hip_runtime.h>
#include <hip/hip_bf16.h>

typedef __attribute__((ext_vector_type(4))) float  f32x4;
typedef __attribute__((ext_vector_type(8))) short  s16x8;

#define D_MODEL 2048
#define SEQ     4096
#define BATCH   4
#define NATOMS  64
#define RANK    6
#define NLAYERS 16
#define NAR     (NATOMS*RANK)     /* 384 */
#define M_TOTAL (BATCH*SEQ)       /* 16384 */

static __device__ __forceinline__ unsigned short f2bf(float x){
    union { float f; unsigned u; } v; v.f = x;
    unsigned r = (v.u + 0x7FFF + ((v.u >> 16) & 1)) >> 16;
    return (unsigned short)r;
}

static __device__ __forceinline__ void gload_lds16(const void* g, void* l) {
    __builtin_amdgcn_global_load_lds(
        (const __attribute__((address_space(1))) unsigned int*)g,
        (__attribute__((address_space(3))) unsigned int*)l, 16, 0, 0);
}

static __device__ __forceinline__ s16x8 cvt8(f32x4 lo, f32x4 hi) {
    union { s16x8 v; unsigned short s[8]; } u;
    u.s[0] = f2bf(lo.x); u.s[1] = f2bf(lo.y); u.s[2] = f2bf(lo.z); u.s[3] = f2bf(lo.w);
    u.s[4] = f2bf(hi.x); u.s[5] = f2bf(hi.y); u.s[6] = f2bf(hi.z); u.s[7] = f2bf(hi.w);
    return u.v;
}

// ---------------------------------------------------------------------------
// Prep: gather layer slice, cast to bf16, lay out K-contiguous.
//   WbfT[n][d]  (n = a*6+r, d = 0..2047)   from A[a, l, d, r]
//   BbfT[p][n]  (p = 0..2047, n = a*6+r)   from B[a, l, r, p]
// ---------------------------------------------------------------------------
__global__ void prep_kernel(const float* __restrict__ A,
                            const float* __restrict__ B,
                            const int*   __restrict__ layer_idx,
                            unsigned short* __restrict__ WbfT,
                            unsigned short* __restrict__ BbfT)
{
    const int l = layer_idx[0];
    int idx = blockIdx.x * 256 + threadIdx.x;
    const int total = NAR * D_MODEL;   // 786432
    if (idx < total) {
        int n = idx / D_MODEL, d = idx % D_MODEL;
        int a = n / RANK, r = n % RANK;
        float v = A[((size_t)(a*NLAYERS + l) * D_MODEL + d) * RANK + r];
        WbfT[idx] = f2bf(v);
    } else {
        idx -= total;
        int p = idx / NAR, n = idx % NAR;
        int a = n / RANK, r = n % RANK;
        float v = B[((size_t)(a*NLAYERS + l) * RANK + r) * D_MODEL + p];
        BbfT[idx] = f2bf(v);
    }
}

// ---------------------------------------------------------------------------
// GEMM1: P[m][n] = f2bf( scale[b, n/6] * sum_d hidden[m][d] * WbfT[n][d] )
//   M=16384, K=2048, N=384.  BM=64, BN=128, BK=64, 4 waves (2x2), dbuf.
//   W: global_load_lds (linear dest, XOR-preswizzled source, XOR read).
//   A: reg-staged fp32->bf16, padded LDS (no swizzle needed).
// ---------------------------------------------------------------------------
__global__ __launch_bounds__(256, 2) void gemm1(
    const float*          __restrict__ hidden,  // [16384][2048] fp32
    const float*          __restrict__ scales,  // [4][64]
    const unsigned short* __restrict__ WbfT,    // [384][2048] bf16
    unsigned short*       __restrict__ P)       // [16384][384] bf16
{
    __shared__ __align__(16) unsigned short Af[2][64*72];   // A bf16, +8 pad
    __shared__ __align__(16) unsigned short Wf[2][128*64];  // W bf16, linear (gload_lds)

    const int m0   = blockIdx.x * 64;
    const int n0   = blockIdx.y * 128;
    const int tid  = threadIdx.x;
    const int lane = tid & 63;
    const int wave = tid >> 6;
    const int wr   = wave >> 1, wc = wave & 1;

    // A staging: thread owns row rA, 16 floats starting at float-col cA
    const int rA = tid >> 2;
    const int cA = (tid & 3) << 4;
    const float* srcA = &hidden[(size_t)(m0 + rA) * D_MODEL + cA];

    // W staging: 16 gload_lds insts of 1KB; wave w does insts i = w*4+j.
    // inst i, lane l -> LDS row r = i*8 + (l>>3), chunk c = l&7 (16B chunks).
    // pre-swizzle source so LDS chunk c holds global chunk c^(r&7).
    const unsigned short* srcW[4];
    int ldsWoff[4];
    #pragma unroll
    for (int j = 0; j < 4; ++j) {
        int i = wave * 4 + j;
        int r = i * 8 + (lane >> 3);
        int c = (lane & 7) ^ (r & 7);
        srcW[j]   = &WbfT[(size_t)(n0 + r) * D_MODEL + c * 8];
        ldsWoff[j] = i * 512;  // shorts
    }

    f32x4 acc[2][4] = {};
    f32x4 g[4];

    // ---- prologue: stage K-tile 0 into buf 0 ----
    #pragma unroll
    for (int q = 0; q < 4; ++q) g[q] = *reinterpret_cast<const f32x4*>(srcA + q * 4);
    srcA += 64;
    #pragma unroll
    for (int j = 0; j < 4; ++j) { gload_lds16(srcW[j], &Wf[0][ldsWoff[j]]); srcW[j] += 64; }
    {
        s16x8 s0 = cvt8(g[0], g[1]);
        s16x8 s1 = cvt8(g[2], g[3]);
        *reinterpret_cast<s16x8*>(&Af[0][rA * 72 + cA])     = s0;
        *reinterpret_cast<s16x8*>(&Af[0][rA * 72 + cA + 8]) = s1;
    }
    __syncthreads();

    int cur = 0;
    for (int t = 0; t < 32; ++t) {
        const bool pf = (t < 31);
        if (pf) {
            #pragma unroll
            for (int q = 0; q < 4; ++q) g[q] = *reinterpret_cast<const f32x4*>(srcA + q * 4);
            srcA += 64;
            #pragma unroll
            for (int j = 0; j < 4; ++j) { gload_lds16(srcW[j], &Wf[cur ^ 1][ldsWoff[j]]); srcW[j] += 64; }
        }
        // ---- compute on buf cur ----
        #pragma unroll
        for (int kk = 0; kk < 2; ++kk) {
            const int krow = kk * 32 + (lane >> 4) * 8;
            const int kch  = krow >> 3;          // global 16B-chunk index 0..7
            s16x8 bfr[4];
            #pragma unroll
            for (int ni = 0; ni < 4; ++ni) {
                int br = wc * 64 + ni * 16 + (lane & 15);
                bfr[ni] = *reinterpret_cast<const s16x8*>(
                    &Wf[cur][br * 64 + ((kch ^ (br & 7)) << 3)]);
            }
            #pragma unroll
            for (int mi = 0; mi < 2; ++mi) {
                int ar = wr * 32 + mi * 16 + (lane & 15);
                s16x8 afr = *reinterpret_cast<const s16x8*>(&Af[cur][ar * 72 + krow]);
                #pragma unroll
                for (int ni = 0; ni < 4; ++ni)
                    acc[mi][ni] = __builtin_amdgcn_mfma_f32_16x16x32_bf16(
                        afr, bfr[ni], acc[mi][ni], 0, 0, 0);
            }
        }
        if (pf) {
            s16x8 s0 = cvt8(g[0], g[1]);
            s16x8 s1 = cvt8(g[2], g[3]);
            *reinterpret_cast<s16x8*>(&Af[cur ^ 1][rA * 72 + cA])     = s0;
            *reinterpret_cast<s16x8*>(&Af[cur ^ 1][rA * 72 + cA + 8]) = s1;
        }
        __syncthreads();
        cur ^= 1;
    }

    // ---- epilogue: scale by atom_scales[b, n/6], store bf16 ----
    const int b    = m0 >> 12;
    const int row0 = m0 + wr * 32;
    const int col0 = n0 + wc * 64;
    #pragma unroll
    for (int ni = 0; ni < 4; ++ni) {
        int col  = col0 + ni * 16 + (lane & 15);
        float sc = scales[b * NATOMS + col / RANK];
        #pragma unroll
        for (int mi = 0; mi < 2; ++mi) {
            #pragma unroll
            for (int r = 0; r < 4; ++r) {
                int row = row0 + mi * 16 + (lane >> 4) * 4 + r;
                P[(size_t)row * NAR + col] = f2bf(acc[mi][ni][r] * sc);
            }
        }
    }
}

// ---------------------------------------------------------------------------
// GEMM2: out[m][p] = sum_n P[m][n] * BbfT[p][n]   (at HBM roofline, unchanged)
//   M=16384, K=384, N=2048.  BM=BN=128, BK=64.
// ---------------------------------------------------------------------------
__global__ __launch_bounds__(256, 2) void gemm2(
    const unsigned short* __restrict__ P,     // [16384][384] bf16
    const unsigned short* __restrict__ BbfT,  // [2048][384] bf16
    float*                __restrict__ out)   // [16384][2048] fp32
{
    __shared__ unsigned short Pt[128][72];
    __shared__ unsigned short Bt[128][72];

    const int m0   = blockIdx.x * 128;
    const int p0   = blockIdx.y * 128;
    const int tid  = threadIdx.x;
    const int lane = tid & 63;
    const int wave = tid >> 6;
    const int wr   = wave >> 1, wc = wave & 1;

    f32x4 acc[4][4] = {};

    for (int k0 = 0; k0 < NAR; k0 += 64) {
        #pragma unroll
        for (int pass = 0; pass < 4; ++pass) {
            int c   = tid + pass * 256;
            int row = c >> 3, c8 = c & 7;
            s16x8 v = *reinterpret_cast<const s16x8*>(
                &P[(size_t)(m0 + row) * NAR + k0 + c8 * 8]);
            *reinterpret_cast<s16x8*>(&Pt[row][c8 * 8]) = v;
        }
        #pragma unroll
        for (int pass = 0; pass < 4; ++pass) {
            int c   = tid + pass * 256;
            int row = c >> 3, c8 = c & 7;
            s16x8 v = *reinterpret_cast<const s16x8*>(
                &BbfT[(size_t)(p0 + row) * NAR + k0 + c8 * 8]);
            *reinterpret_cast<s16x8*>(&Bt[row][c8 * 8]) = v;
        }
        __syncthreads();

        #pragma unroll
        for (int kk = 0; kk < 64; kk += 32) {
            const int krow = kk + (lane >> 4) * 8;
            s16x8 a_frag[4], b_frag[4];
            #pragma unroll
            for (int mi = 0; mi < 4; ++mi)
                a_frag[mi] = *reinterpret_cast<const s16x8*>(
                    &Pt[wr * 64 + mi * 16 + (lane & 15)][krow]);
            #pragma unroll
            for (int ni = 0; ni < 4; ++ni)
                b_frag[ni] = *reinterpret_cast<const s16x8*>(
                    &Bt[wc * 64 + ni * 16 + (lane & 15)][krow]);
            #pragma unroll
            for (int mi = 0; mi < 4; ++mi)
                #pragma unroll
                for (int ni = 0; ni < 4; ++ni)
                    acc[mi][ni] = __builtin_amdgcn_mfma_f32_16x16x32_bf16(
                        a_frag[mi], b_frag[ni], acc[mi][ni], 0, 0, 0);
        }
        __syncthreads();
    }

    const int row0 = m0 + wr * 64;
    const int col0 = p0 + wc * 64;
    #pragma unroll
    for (int mi = 0; mi < 4; ++mi) {
        #pragma unroll
        for (int ni = 0; ni < 4; ++ni) {
            int col = col0 + ni * 16 + (lane & 15);
            #pragma unroll
            for (int r = 0; r < 4; ++r) {
                int row = row0 + mi * 16 + (lane >> 4) * 4 + r;
                out[(size_t)row * D_MODEL + col] = acc[mi][ni][r];
            }
        }
    }
}

extern "C" void kernel_launch(void* const* d_in, const int* in_sizes, int n_in,
                              void* d_out, int out_size, void* d_ws, size_t ws_size,
                              hipStream_t stream)
{
    const float* hidden    = (const float*)d_in[0];
    const float* scales    = (const float*)d_in[1];
    const float* A         = (const float*)d_in[2];
    const float* B         = (const float*)d_in[3];
    const int*   layer_idx = (const int*)d_in[4];
    float* out = (float*)d_out;

    unsigned short* WbfT = (unsigned short*)d_ws;            // [384][2048]
    unsigned short* BbfT = WbfT + (size_t)NAR * D_MODEL;     // [2048][384]
    unsigned short* P    = BbfT + (size_t)D_MODEL * NAR;     // [16384][384]

    prep_kernel<<<(2 * NAR * D_MODEL) / 256, 256, 0, stream>>>(A, B, layer_idx, WbfT, BbfT);
    gemm1<<<dim3(M_TOTAL / 64, NAR / 128), 256, 0, stream>>>(hidden, scales, WbfT, P);
    gemm2<<<dim3(M_TOTAL / 128, D_MODEL / 128), 256, 0, stream>>>(P, BbfT, out);
}